// Round 1
// 254.202 us; speedup vs baseline: 1.0012x; 1.0012x over previous
//
#include <hip/hip_runtime.h>
#include <hip/hip_bf16.h>
#include <hip/hip_fp16.h>

// ---------------------------------------------------------------------------
// 2-layer GAT, N=50000, E=1.6M (+N self loops).
// CSR build (counting sort) -> GEMM1 [fp16 MFMA, fused alpha] -> agg1(fp16 out)
//  -> GEMM2 [fp16 MFMA, fused alpha] -> agg2 -> d_out.
// Softmax computed without max-shift (shift-invariant; |e| ~ 1.5).
// R2: hierarchical scan. R3: col[] uint16. R4: fp16 gather payload.
// R6: counting-sort CSR build. R9: MFMA GEMMs (v_mfma_f32_16x16x32_f16).
// R10: agg rewrite — half-wave (agg1) / quarter-wave (agg2) per edge row,
//      8B f16x4 gathers, per-lane alpha (asrc broadcast-load + exp in place,
//      no 2-phase exp dedup, no p-shuffles). ~2x fewer VALU instr/edge.
// ---------------------------------------------------------------------------

#define LRELU_SLOPE 0.2f
#define NBMAX 200        // max dst buckets (N <= 51200)
#define NBLK  512        // blocks in hist/scatter passes
#define BCAP  16384      // per-bucket record capacity (mean ~8163)
#define CAPIMG 16384     // csr_scatter LDS image entries

typedef _Float16 f16x8 __attribute__((ext_vector_type(8)));
typedef _Float16 f16x4 __attribute__((ext_vector_type(4)));
typedef float f32x4 __attribute__((ext_vector_type(4)));

// ---------------- CSR build ----------------

__global__ __launch_bounds__(256) void hist_kernel(const int* __restrict__ ei_dst,
                                                   int* __restrict__ hist, int E, int chunk) {
    __shared__ int h[NBMAX];
    int t = threadIdx.x;
    for (int i = t; i < NBMAX; i += 256) h[i] = 0;
    __syncthreads();
    int begin = blockIdx.x * chunk;
    int endE = min(E, begin + chunk);
    for (int e = begin + t; e < endE; e += 256) atomicAdd(&h[ei_dst[e] >> 8], 1);
    __syncthreads();
    for (int i = t; i < NBMAX; i += 256) hist[i * NBLK + blockIdx.x] = h[i];
}

__global__ __launch_bounds__(512) void bucket_scan_kernel(int* __restrict__ hist,
                                                          int* __restrict__ gfill) {
    __shared__ int buf[2][NBLK];
    int b = blockIdx.x, t = threadIdx.x;
    buf[0][t] = hist[b * NBLK + t];
    __syncthreads();
    int pi = 0;
#pragma unroll
    for (int off = 1; off < NBLK; off <<= 1) {
        int v = buf[pi][t];
        if (t >= off) v += buf[pi][t - off];
        buf[pi ^ 1][t] = v;
        __syncthreads();
        pi ^= 1;
    }
    hist[b * NBLK + t] = (t == 0) ? 0 : buf[pi][t - 1];
    if (t == 0) gfill[b] = buf[pi][NBLK - 1];
}

__global__ __launch_bounds__(256) void scatter2_kernel(const int* __restrict__ ei_src,
                                                       const int* __restrict__ ei_dst,
                                                       const int* __restrict__ hist,
                                                       unsigned int* __restrict__ records,
                                                       int E, int chunk) {
    __shared__ int base[NBMAX];
    __shared__ int lcnt[NBMAX];
    int t = threadIdx.x;
    for (int i = t; i < NBMAX; i += 256) {
        base[i] = hist[i * NBLK + blockIdx.x];
        lcnt[i] = 0;
    }
    __syncthreads();
    int begin = blockIdx.x * chunk;
    int endE = min(E, begin + chunk);
    for (int e = begin + t; e < endE; e += 256) {
        int s = ei_src[e], d = ei_dst[e];
        int bkt = d >> 8;
        unsigned int rec = (unsigned int)d | ((unsigned int)s << 16);
        int r = atomicAdd(&lcnt[bkt], 1);
        records[(size_t)bkt * BCAP + base[bkt] + r] = rec;
    }
}

__global__ __launch_bounds__(256) void deg_kernel(const unsigned int* __restrict__ records,
                                                  const int* __restrict__ gfill,
                                                  int* __restrict__ deg, int N) {
    __shared__ int cnt[256];
    int t = threadIdx.x, b = blockIdx.x;
    cnt[t] = 1;
    __syncthreads();
    int c = gfill[b];
    const unsigned int* r = records + (size_t)b * BCAP;
    for (int i = t; i < c; i += 256) atomicAdd(&cnt[r[i] & 255], 1);
    __syncthreads();
    int gi = (b << 8) + t;
    if (gi < N) deg[gi] = cnt[t];
}

__global__ __launch_bounds__(256) void scan_blocksums_kernel(const int* __restrict__ gfill,
                                                             int* __restrict__ bsums,
                                                             int* __restrict__ row_ptr,
                                                             int nblocks, int n, int total) {
    __shared__ int buf[2][256];
    int t = threadIdx.x;
    int v0 = 0;
    if (t < nblocks) v0 = gfill[t] + min(256, n - (t << 8));
    buf[0][t] = v0;
    __syncthreads();
    int pi = 0;
#pragma unroll
    for (int off = 1; off < 256; off <<= 1) {
        int v = buf[pi][t];
        if (t >= off) v += buf[pi][t - off];
        buf[pi ^ 1][t] = v;
        __syncthreads();
        pi ^= 1;
    }
    if (t < nblocks) bsums[t] = (t == 0) ? 0 : buf[pi][t - 1];
    if (t == 0) row_ptr[n] = total;
}

__global__ __launch_bounds__(256) void scan_down_kernel(const int* __restrict__ deg,
                                                        const int* __restrict__ blockSums,
                                                        int* __restrict__ row_ptr, int n) {
    __shared__ int buf[2][256];
    int t = threadIdx.x;
    int i = blockIdx.x * 256 + t;
    int d = (i < n) ? deg[i] : 0;
    buf[0][t] = d;
    __syncthreads();
    int pi = 0;
#pragma unroll
    for (int off = 1; off < 256; off <<= 1) {
        int v = buf[pi][t];
        if (t >= off) v += buf[pi][t - off];
        buf[pi ^ 1][t] = v;
        __syncthreads();
        pi ^= 1;
    }
    if (i < n) row_ptr[i] = blockSums[blockIdx.x] + buf[pi][t] - d;
}

__global__ __launch_bounds__(256) void csr_scatter_kernel(const unsigned int* __restrict__ records,
                                                          const int* __restrict__ gfill,
                                                          const int* __restrict__ row_ptr,
                                                          unsigned short* __restrict__ col,
                                                          int N) {
    __shared__ unsigned short img[CAPIMG];
    __shared__ int lfill[256];
    int t = threadIdx.x, b = blockIdx.x;
    int bBase = b << 8;
    int bEnd = min(bBase + 256, N);
    int rbase = row_ptr[bBase];
    int size = row_ptr[bEnd] - rbase;
    bool lds = (size <= CAPIMG);
    int gi = bBase + t;
    if (gi < bEnd) {
        int rp = row_ptr[gi];
        int local = rp - rbase;
        lfill[t] = local + 1;  // slot 0 = self loop
        if (lds) img[local] = (unsigned short)gi;
        else col[rp] = (unsigned short)gi;
    }
    __syncthreads();
    int c = gfill[b];
    const unsigned int* r = records + (size_t)b * BCAP;
    for (int i = t; i < c; i += 256) {
        unsigned int rec = r[i];
        int d8 = rec & 255;
        unsigned short s = (unsigned short)(rec >> 16);
        int p = atomicAdd(&lfill[d8], 1);
        if (lds) img[p] = s;
        else col[rbase + p] = s;
    }
    __syncthreads();
    if (lds) {
        for (int i = t; i < size; i += 256) col[rbase + i] = img[i];
    }
}

// ---------------- GEMM1: X fp32 [n,128] @ W1 [128,128] -> h1h fp16 + alphas ----
// Per block: 64 rows (4 waves x 16). MFMA 16x16x32 f16; W^T staged fp16 LDS.

__global__ __launch_bounds__(256) void gemm1_mfma_kernel(const float* __restrict__ X,
                                                         const float* __restrict__ W,
                                                         __half* __restrict__ outh,
                                                         const float* __restrict__ a_src,
                                                         const float* __restrict__ a_dst,
                                                         float* __restrict__ as_out,
                                                         float* __restrict__ ad_out, int nrows) {
    constexpr int KP = 136;  // padded k-stride in halves
    __shared__ _Float16 wlds[128 * KP];  // wlds[n][k] = W[k][n]
    int t = threadIdx.x;
    int wv = t >> 6, lane = t & 63;
    int quad = lane >> 4, m16 = lane & 15;
    // stage W^T as fp16
    for (int i = t; i < 4096; i += 256) {  // 128*128/4
        int k = i >> 5;
        int n0 = (i & 31) << 2;
        float4 v = *(const float4*)(W + k * 128 + n0);
        wlds[(n0 + 0) * KP + k] = (_Float16)v.x;
        wlds[(n0 + 1) * KP + k] = (_Float16)v.y;
        wlds[(n0 + 2) * KP + k] = (_Float16)v.z;
        wlds[(n0 + 3) * KP + k] = (_Float16)v.w;
    }
    __syncthreads();

    int row = blockIdx.x * 64 + wv * 16 + m16;
    int rowC = min(row, nrows - 1);
    const float* xp = X + (size_t)rowC * 128;

    f32x4 acc[8];
#pragma unroll
    for (int nt = 0; nt < 8; ++nt) acc[nt] = (f32x4)0.f;

    for (int kt = 0; kt < 128; kt += 32) {
        float4 v0 = *(const float4*)(xp + kt + quad * 8);
        float4 v1 = *(const float4*)(xp + kt + quad * 8 + 4);
        f16x8 af;
        af[0] = (_Float16)v0.x; af[1] = (_Float16)v0.y;
        af[2] = (_Float16)v0.z; af[3] = (_Float16)v0.w;
        af[4] = (_Float16)v1.x; af[5] = (_Float16)v1.y;
        af[6] = (_Float16)v1.z; af[7] = (_Float16)v1.w;
#pragma unroll
        for (int nt = 0; nt < 8; ++nt) {
            f16x8 bf = *(const f16x8*)(&wlds[(nt * 16 + m16) * KP + kt + quad * 8]);
            acc[nt] = __builtin_amdgcn_mfma_f32_16x16x32_f16(af, bf, acc[nt], 0, 0, 0);
        }
    }

    // per-lane alpha coefficients for its column in each tile
    float aS[8], aD[8];
#pragma unroll
    for (int nt = 0; nt < 8; ++nt) {
        aS[nt] = a_src[nt * 16 + m16];
        aD[nt] = a_dst[nt * 16 + m16];
    }
    int rowBaseW = blockIdx.x * 64 + wv * 16;
#pragma unroll
    for (int r = 0; r < 4; ++r) {
        int orow = rowBaseW + quad * 4 + r;
        bool ov = orow < nrows;
        // fp16 store of C row segment
        if (ov) {
#pragma unroll
            for (int nt = 0; nt < 8; ++nt)
                outh[(size_t)orow * 128 + nt * 16 + m16] = __float2half(acc[nt][r]);
        }
        // alpha: per head h, reduce cols (2 tiles x 16 lanes)
#pragma unroll
        for (int h = 0; h < 4; ++h) {
            float ss = acc[2 * h][r] * aS[2 * h] + acc[2 * h + 1][r] * aS[2 * h + 1];
            float dd = acc[2 * h][r] * aD[2 * h] + acc[2 * h + 1][r] * aD[2 * h + 1];
#pragma unroll
            for (int o = 1; o < 16; o <<= 1) {
                ss += __shfl_xor(ss, o, 64);
                dd += __shfl_xor(dd, o, 64);
            }
            if (ov && m16 == h) {
                as_out[orow * 4 + h] = ss;
                ad_out[orow * 4 + h] = dd;
            }
        }
    }
}

// ---------------- GEMM2: h2in fp16 [n,128] @ W2 [128,64] -> h2bh fp16 + alphas --

__global__ __launch_bounds__(256) void gemm2_mfma_kernel(const __half* __restrict__ Xh,
                                                         const float* __restrict__ W,
                                                         __half* __restrict__ outh,
                                                         const float* __restrict__ a_src,
                                                         const float* __restrict__ a_dst,
                                                         float* __restrict__ as_out,
                                                         float* __restrict__ ad_out, int nrows) {
    constexpr int KP = 136;
    __shared__ _Float16 wlds[64 * KP];  // wlds[n][k] = W[k][n]
    int t = threadIdx.x;
    int wv = t >> 6, lane = t & 63;
    int quad = lane >> 4, m16 = lane & 15;
    for (int i = t; i < 2048; i += 256) {  // 128*64/4
        int k = i >> 4;
        int n0 = (i & 15) << 2;
        float4 v = *(const float4*)(W + k * 64 + n0);
        wlds[(n0 + 0) * KP + k] = (_Float16)v.x;
        wlds[(n0 + 1) * KP + k] = (_Float16)v.y;
        wlds[(n0 + 2) * KP + k] = (_Float16)v.z;
        wlds[(n0 + 3) * KP + k] = (_Float16)v.w;
    }
    __syncthreads();

    int row = blockIdx.x * 64 + wv * 16 + m16;
    int rowC = min(row, nrows - 1);
    const _Float16* xp = (const _Float16*)Xh + (size_t)rowC * 128;

    f32x4 acc[4];
#pragma unroll
    for (int nt = 0; nt < 4; ++nt) acc[nt] = (f32x4)0.f;

    for (int kt = 0; kt < 128; kt += 32) {
        f16x8 af = *(const f16x8*)(xp + kt + quad * 8);
#pragma unroll
        for (int nt = 0; nt < 4; ++nt) {
            f16x8 bf = *(const f16x8*)(&wlds[(nt * 16 + m16) * KP + kt + quad * 8]);
            acc[nt] = __builtin_amdgcn_mfma_f32_16x16x32_f16(af, bf, acc[nt], 0, 0, 0);
        }
    }

    float aS[4], aD[4];
#pragma unroll
    for (int nt = 0; nt < 4; ++nt) {
        aS[nt] = a_src[nt * 16 + m16];
        aD[nt] = a_dst[nt * 16 + m16];
    }
    int rowBaseW = blockIdx.x * 64 + wv * 16;
#pragma unroll
    for (int r = 0; r < 4; ++r) {
        int orow = rowBaseW + quad * 4 + r;
        bool ov = orow < nrows;
        if (ov) {
#pragma unroll
            for (int nt = 0; nt < 4; ++nt)
                outh[(size_t)orow * 64 + nt * 16 + m16] = __float2half(acc[nt][r]);
        }
        float ss = 0.f, dd = 0.f;
#pragma unroll
        for (int nt = 0; nt < 4; ++nt) {
            ss = fmaf(acc[nt][r], aS[nt], ss);
            dd = fmaf(acc[nt][r], aD[nt], dd);
        }
#pragma unroll
        for (int o = 1; o < 16; o <<= 1) {
            ss += __shfl_xor(ss, o, 64);
            dd += __shfl_xor(dd, o, 64);
        }
        if (ov && m16 == 0) {
            as_out[orow] = ss;
            ad_out[orow] = dd;
        }
    }
}

// ---------------- aggregation ----------------

// layer 1: one wave per dst node. Half-wave per edge row: lane = {half(1),m(5)},
// lane m covers channels [4m,4m+4) via one 8B f16x4 gather. Alpha computed
// per-lane (asrc[s*4+head] is an 8-lane broadcast load); denominator reduced
// with a single shfl_xor(32) at the end. Writes fp16 h2in (bias+relu applied).
__global__ __launch_bounds__(256) void agg1_kernel(const __half* __restrict__ h1h,
                                                   const float* __restrict__ asrc,
                                                   const float* __restrict__ adst,
                                                   const int* __restrict__ row_ptr,
                                                   const unsigned short* __restrict__ col,
                                                   const float* __restrict__ b1,
                                                   __half* __restrict__ out, int n) {
    int wave = threadIdx.x >> 6;
    int lane = threadIdx.x & 63;
    int node = blockIdx.x * 4 + wave;
    if (node >= n) return;
    int half = lane >> 5;
    int m = lane & 31;           // f16x4 chunk index within 128-ch row
    int head = m >> 3;           // 4 heads x 8 chunks
    const f16x4* __restrict__ h4 = (const f16x4*)h1h;
    float ad = adst[node * 4 + head];
    int start = row_ptr[node], end = row_ptr[node + 1];
    float a0c = 0.f, a1c = 0.f, a2c = 0.f, a3c = 0.f, s = 0.f;
    for (int base = start; base < end; base += 64) {
        int cnt = min(64, end - base);
        int idx = base + lane;
        int myS = (idx < end) ? (int)col[idx] : 0;
        for (int j = 0; j < cnt; j += 4) {   // 4 edges/iter, 2 per half
            int jj0 = j + half;
            int jj1 = j + 2 + half;
            int s0 = __shfl(myS, jj0, 64);
            int s1 = __shfl(myS, jj1, 64);
            f16x4 v0 = h4[s0 * 32 + m];
            f16x4 v1 = h4[s1 * 32 + m];
            float e0 = asrc[s0 * 4 + head] + ad;
            float e1 = asrc[s1 * 4 + head] + ad;
            e0 = fmaxf(e0, LRELU_SLOPE * e0);
            e1 = fmaxf(e1, LRELU_SLOPE * e1);
            float p0 = (jj0 < cnt) ? __expf(e0) : 0.f;
            float p1 = (jj1 < cnt) ? __expf(e1) : 0.f;
            a0c = fmaf(p0, (float)v0[0], a0c);
            a1c = fmaf(p0, (float)v0[1], a1c);
            a2c = fmaf(p0, (float)v0[2], a2c);
            a3c = fmaf(p0, (float)v0[3], a3c);
            a0c = fmaf(p1, (float)v1[0], a0c);
            a1c = fmaf(p1, (float)v1[1], a1c);
            a2c = fmaf(p1, (float)v1[2], a2c);
            a3c = fmaf(p1, (float)v1[3], a3c);
            s += p0 + p1;
        }
    }
    a0c += __shfl_xor(a0c, 32, 64);
    a1c += __shfl_xor(a1c, 32, 64);
    a2c += __shfl_xor(a2c, 32, 64);
    a3c += __shfl_xor(a3c, 32, 64);
    s   += __shfl_xor(s, 32, 64);
    if (half == 0) {
        float inv = 1.f / (s + 1e-16f);
        float4 bb = ((const float4*)b1)[m];
        f16x4 o;
        o[0] = (_Float16)fmaxf(fmaf(a0c, inv, bb.x), 0.f);  // relu between layers
        o[1] = (_Float16)fmaxf(fmaf(a1c, inv, bb.y), 0.f);
        o[2] = (_Float16)fmaxf(fmaf(a2c, inv, bb.z), 0.f);
        o[3] = (_Float16)fmaxf(fmaf(a3c, inv, bb.w), 0.f);
        ((f16x4*)out)[node * 32 + m] = o;
    }
}

// layer 2: one wave per dst node. Quarter-wave per edge row: lane = {q(2),m(4)},
// lane m covers channels [4m,4m+4) of 64; 8 edges in flight per iteration.
__global__ __launch_bounds__(256) void agg2_kernel(const __half* __restrict__ h2bh,
                                                   const float* __restrict__ asrc,
                                                   const float* __restrict__ adst,
                                                   const int* __restrict__ row_ptr,
                                                   const unsigned short* __restrict__ col,
                                                   const float* __restrict__ b2,
                                                   float* __restrict__ out, int n) {
    int wave = threadIdx.x >> 6;
    int lane = threadIdx.x & 63;
    int node = blockIdx.x * 4 + wave;
    if (node >= n) return;
    int q = lane >> 4;
    int m = lane & 15;           // f16x4 chunk index within 64-ch row
    const f16x4* __restrict__ h4 = (const f16x4*)h2bh;
    float ad = adst[node];
    int start = row_ptr[node], end = row_ptr[node + 1];
    float a0c = 0.f, a1c = 0.f, a2c = 0.f, a3c = 0.f, s = 0.f;
    for (int base = start; base < end; base += 64) {
        int cnt = min(64, end - base);
        int idx = base + lane;
        int myS = (idx < end) ? (int)col[idx] : 0;
        for (int j = 0; j < cnt; j += 8) {   // 8 edges/iter, 2 per quarter
            int jj0 = j + q;
            int jj1 = j + 4 + q;
            int s0 = __shfl(myS, jj0, 64);
            int s1 = __shfl(myS, jj1, 64);
            f16x4 v0 = h4[s0 * 16 + m];
            f16x4 v1 = h4[s1 * 16 + m];
            float e0 = asrc[s0] + ad;
            float e1 = asrc[s1] + ad;
            e0 = fmaxf(e0, LRELU_SLOPE * e0);
            e1 = fmaxf(e1, LRELU_SLOPE * e1);
            float p0 = (jj0 < cnt) ? __expf(e0) : 0.f;
            float p1 = (jj1 < cnt) ? __expf(e1) : 0.f;
            a0c = fmaf(p0, (float)v0[0], a0c);
            a1c = fmaf(p0, (float)v0[1], a1c);
            a2c = fmaf(p0, (float)v0[2], a2c);
            a3c = fmaf(p0, (float)v0[3], a3c);
            a0c = fmaf(p1, (float)v1[0], a0c);
            a1c = fmaf(p1, (float)v1[1], a1c);
            a2c = fmaf(p1, (float)v1[2], a2c);
            a3c = fmaf(p1, (float)v1[3], a3c);
            s += p0 + p1;
        }
    }
#pragma unroll
    for (int o = 16; o <= 32; o <<= 1) {
        a0c += __shfl_xor(a0c, o, 64);
        a1c += __shfl_xor(a1c, o, 64);
        a2c += __shfl_xor(a2c, o, 64);
        a3c += __shfl_xor(a3c, o, 64);
        s   += __shfl_xor(s, o, 64);
    }
    if (lane < 16) {
        float inv = 1.f / (s + 1e-16f);
        float4 bb = ((const float4*)b2)[m];
        float4 o;
        o.x = fmaf(a0c, inv, bb.x);
        o.y = fmaf(a1c, inv, bb.y);
        o.z = fmaf(a2c, inv, bb.z);
        o.w = fmaf(a3c, inv, bb.w);
        ((float4*)(out + (size_t)node * 64))[m] = o;
    }
}

// ---------------- launch ----------------

extern "C" void kernel_launch(void* const* d_in, const int* in_sizes, int n_in,
                              void* d_out, int out_size, void* d_ws, size_t ws_size,
                              hipStream_t stream) {
    const float* x      = (const float*)d_in[0];
    const int*   ei     = (const int*)d_in[1];
    const float* W1     = (const float*)d_in[2];
    const float* a_src1 = (const float*)d_in[3];
    const float* a_dst1 = (const float*)d_in[4];
    const float* b1     = (const float*)d_in[5];
    const float* W2     = (const float*)d_in[6];
    const float* a_src2 = (const float*)d_in[7];
    const float* a_dst2 = (const float*)d_in[8];
    const float* b2     = (const float*)d_in[9];
    float* out = (float*)d_out;

    const int N = in_sizes[0] / 128;
    const int E = in_sizes[1] / 2;
    const int total = E + N;
    const int nBuckets = (N + 255) >> 8;   // 196

    char* ws = (char*)d_ws;
    size_t off = 0;
    auto alloc = [&](size_t bytes) {
        void* p = ws + off;
        off += (bytes + 255) & ~(size_t)255;
        return p;
    };
    // Region A: records+hist (CSR build), then h2in fp16 (agg1->gemm2).
    float* regionA = (float*)alloc((size_t)N * 128 * 4);
    __half* h1h   = (__half*)alloc((size_t)N * 128 * 2);
    __half* h2bh  = (__half*)alloc((size_t)N * 64 * 2);
    float* asrc1  = (float*)alloc((size_t)N * 4 * 4);
    float* adst1  = (float*)alloc((size_t)N * 4 * 4);
    float* asrc2  = (float*)alloc((size_t)N * 4);
    float* adst2  = (float*)alloc((size_t)N * 4);
    int*   deg    = (int*)alloc((size_t)N * 4);
    int*   row_ptr= (int*)alloc((size_t)(N + 1) * 4);
    int*   gfill  = (int*)alloc((size_t)nBuckets * 4);
    int*   bsums  = (int*)alloc((size_t)nBuckets * 4);
    unsigned short* col = (unsigned short*)alloc((size_t)total * 2);

    unsigned int* records = (unsigned int*)regionA;          // 12.8MB
    int* hist = (int*)(regionA + (size_t)NBMAX * BCAP);      // +400KB
    __half* h2in = (__half*)regionA;                         // after CSR build done
    (void)ws_size; (void)n_in; (void)out_size;

    const int* ei_src = ei;
    const int* ei_dst = ei + E;

    // CSR build (counting sort by dst bucket)
    const int chunk = (E + NBLK - 1) / NBLK;
    hist_kernel<<<NBLK, 256, 0, stream>>>(ei_dst, hist, E, chunk);
    bucket_scan_kernel<<<nBuckets, NBLK, 0, stream>>>(hist, gfill);
    scatter2_kernel<<<NBLK, 256, 0, stream>>>(ei_src, ei_dst, hist, records, E, chunk);
    deg_kernel<<<nBuckets, 256, 0, stream>>>(records, gfill, deg, N);
    scan_blocksums_kernel<<<1, 256, 0, stream>>>(gfill, bsums, row_ptr, nBuckets, N, total);
    scan_down_kernel<<<nBuckets, 256, 0, stream>>>(deg, bsums, row_ptr, N);
    csr_scatter_kernel<<<nBuckets, 256, 0, stream>>>(records, gfill, row_ptr, col, N);

    // layer 1
    gemm1_mfma_kernel<<<(N + 63) / 64, 256, 0, stream>>>(x, W1, h1h, a_src1, a_dst1,
                                                         asrc1, adst1, N);
    agg1_kernel<<<(N + 3) / 4, 256, 0, stream>>>(h1h, asrc1, adst1,
                                                 row_ptr, col, b1, h2in, N);

    // layer 2
    gemm2_mfma_kernel<<<(N + 63) / 64, 256, 0, stream>>>(h2in, W2, h2bh, a_src2, a_dst2,
                                                         asrc2, adst2, N);
    agg2_kernel<<<(N + 3) / 4, 256, 0, stream>>>(h2bh, asrc2, adst2,
                                                 row_ptr, col, b2, out, N);
}

// Round 2
// 247.025 us; speedup vs baseline: 1.0302x; 1.0291x over previous
//
#include <hip/hip_runtime.h>
#include <hip/hip_bf16.h>
#include <hip/hip_fp16.h>

// ---------------------------------------------------------------------------
// 2-layer GAT, N=50000, E=1.6M (+N self loops).
// CSR build (counting sort) -> GEMM1 [fp16 MFMA, fused alpha] -> agg1(fp16 out)
//  -> GEMM2 [fp16 MFMA, fused alpha] -> agg2 -> d_out.
// Softmax computed without max-shift (shift-invariant; |e| ~ 1.5).
// R2: hierarchical scan. R3: col[] uint16. R4: fp16 gather payload.
// R6: counting-sort CSR build. R9: MFMA GEMMs (v_mfma_f32_16x16x32_f16).
// R10: agg rewrite — half-wave (agg1) / quarter-wave (agg2) per edge row,
//      8B f16x4 gathers, per-lane alpha. R11: 12-edge software-pipelined
//      batches (6 row + 6 asrc gathers in flight per lane), lshl_or address
//      math, 32-bit offsets. Discriminates latency-bound vs LLC-BW-bound.
// ---------------------------------------------------------------------------

#define LRELU_SLOPE 0.2f
#define NBMAX 200        // max dst buckets (N <= 51200)
#define NBLK  512        // blocks in hist/scatter passes
#define BCAP  16384      // per-bucket record capacity (mean ~8163)
#define CAPIMG 16384     // csr_scatter LDS image entries

typedef _Float16 f16x8 __attribute__((ext_vector_type(8)));
typedef _Float16 f16x4 __attribute__((ext_vector_type(4)));
typedef float f32x4 __attribute__((ext_vector_type(4)));

// ---------------- CSR build ----------------

__global__ __launch_bounds__(256) void hist_kernel(const int* __restrict__ ei_dst,
                                                   int* __restrict__ hist, int E, int chunk) {
    __shared__ int h[NBMAX];
    int t = threadIdx.x;
    for (int i = t; i < NBMAX; i += 256) h[i] = 0;
    __syncthreads();
    int begin = blockIdx.x * chunk;
    int endE = min(E, begin + chunk);
    for (int e = begin + t; e < endE; e += 256) atomicAdd(&h[ei_dst[e] >> 8], 1);
    __syncthreads();
    for (int i = t; i < NBMAX; i += 256) hist[i * NBLK + blockIdx.x] = h[i];
}

__global__ __launch_bounds__(512) void bucket_scan_kernel(int* __restrict__ hist,
                                                          int* __restrict__ gfill) {
    __shared__ int buf[2][NBLK];
    int b = blockIdx.x, t = threadIdx.x;
    buf[0][t] = hist[b * NBLK + t];
    __syncthreads();
    int pi = 0;
#pragma unroll
    for (int off = 1; off < NBLK; off <<= 1) {
        int v = buf[pi][t];
        if (t >= off) v += buf[pi][t - off];
        buf[pi ^ 1][t] = v;
        __syncthreads();
        pi ^= 1;
    }
    hist[b * NBLK + t] = (t == 0) ? 0 : buf[pi][t - 1];
    if (t == 0) gfill[b] = buf[pi][NBLK - 1];
}

__global__ __launch_bounds__(256) void scatter2_kernel(const int* __restrict__ ei_src,
                                                       const int* __restrict__ ei_dst,
                                                       const int* __restrict__ hist,
                                                       unsigned int* __restrict__ records,
                                                       int E, int chunk) {
    __shared__ int base[NBMAX];
    __shared__ int lcnt[NBMAX];
    int t = threadIdx.x;
    for (int i = t; i < NBMAX; i += 256) {
        base[i] = hist[i * NBLK + blockIdx.x];
        lcnt[i] = 0;
    }
    __syncthreads();
    int begin = blockIdx.x * chunk;
    int endE = min(E, begin + chunk);
    for (int e = begin + t; e < endE; e += 256) {
        int s = ei_src[e], d = ei_dst[e];
        int bkt = d >> 8;
        unsigned int rec = (unsigned int)d | ((unsigned int)s << 16);
        int r = atomicAdd(&lcnt[bkt], 1);
        records[(size_t)bkt * BCAP + base[bkt] + r] = rec;
    }
}

__global__ __launch_bounds__(256) void deg_kernel(const unsigned int* __restrict__ records,
                                                  const int* __restrict__ gfill,
                                                  int* __restrict__ deg, int N) {
    __shared__ int cnt[256];
    int t = threadIdx.x, b = blockIdx.x;
    cnt[t] = 1;
    __syncthreads();
    int c = gfill[b];
    const unsigned int* r = records + (size_t)b * BCAP;
    for (int i = t; i < c; i += 256) atomicAdd(&cnt[r[i] & 255], 1);
    __syncthreads();
    int gi = (b << 8) + t;
    if (gi < N) deg[gi] = cnt[t];
}

__global__ __launch_bounds__(256) void scan_blocksums_kernel(const int* __restrict__ gfill,
                                                             int* __restrict__ bsums,
                                                             int* __restrict__ row_ptr,
                                                             int nblocks, int n, int total) {
    __shared__ int buf[2][256];
    int t = threadIdx.x;
    int v0 = 0;
    if (t < nblocks) v0 = gfill[t] + min(256, n - (t << 8));
    buf[0][t] = v0;
    __syncthreads();
    int pi = 0;
#pragma unroll
    for (int off = 1; off < 256; off <<= 1) {
        int v = buf[pi][t];
        if (t >= off) v += buf[pi][t - off];
        buf[pi ^ 1][t] = v;
        __syncthreads();
        pi ^= 1;
    }
    if (t < nblocks) bsums[t] = (t == 0) ? 0 : buf[pi][t - 1];
    if (t == 0) row_ptr[n] = total;
}

__global__ __launch_bounds__(256) void scan_down_kernel(const int* __restrict__ deg,
                                                        const int* __restrict__ blockSums,
                                                        int* __restrict__ row_ptr, int n) {
    __shared__ int buf[2][256];
    int t = threadIdx.x;
    int i = blockIdx.x * 256 + t;
    int d = (i < n) ? deg[i] : 0;
    buf[0][t] = d;
    __syncthreads();
    int pi = 0;
#pragma unroll
    for (int off = 1; off < 256; off <<= 1) {
        int v = buf[pi][t];
        if (t >= off) v += buf[pi][t - off];
        buf[pi ^ 1][t] = v;
        __syncthreads();
        pi ^= 1;
    }
    if (i < n) row_ptr[i] = blockSums[blockIdx.x] + buf[pi][t] - d;
}

__global__ __launch_bounds__(256) void csr_scatter_kernel(const unsigned int* __restrict__ records,
                                                          const int* __restrict__ gfill,
                                                          const int* __restrict__ row_ptr,
                                                          unsigned short* __restrict__ col,
                                                          int N) {
    __shared__ unsigned short img[CAPIMG];
    __shared__ int lfill[256];
    int t = threadIdx.x, b = blockIdx.x;
    int bBase = b << 8;
    int bEnd = min(bBase + 256, N);
    int rbase = row_ptr[bBase];
    int size = row_ptr[bEnd] - rbase;
    bool lds = (size <= CAPIMG);
    int gi = bBase + t;
    if (gi < bEnd) {
        int rp = row_ptr[gi];
        int local = rp - rbase;
        lfill[t] = local + 1;  // slot 0 = self loop
        if (lds) img[local] = (unsigned short)gi;
        else col[rp] = (unsigned short)gi;
    }
    __syncthreads();
    int c = gfill[b];
    const unsigned int* r = records + (size_t)b * BCAP;
    for (int i = t; i < c; i += 256) {
        unsigned int rec = r[i];
        int d8 = rec & 255;
        unsigned short s = (unsigned short)(rec >> 16);
        int p = atomicAdd(&lfill[d8], 1);
        if (lds) img[p] = s;
        else col[rbase + p] = s;
    }
    __syncthreads();
    if (lds) {
        for (int i = t; i < size; i += 256) col[rbase + i] = img[i];
    }
}

// ---------------- GEMM1: X fp32 [n,128] @ W1 [128,128] -> h1h fp16 + alphas ----
// Per block: 64 rows (4 waves x 16). MFMA 16x16x32 f16; W^T staged fp16 LDS.

__global__ __launch_bounds__(256) void gemm1_mfma_kernel(const float* __restrict__ X,
                                                         const float* __restrict__ W,
                                                         __half* __restrict__ outh,
                                                         const float* __restrict__ a_src,
                                                         const float* __restrict__ a_dst,
                                                         float* __restrict__ as_out,
                                                         float* __restrict__ ad_out, int nrows) {
    constexpr int KP = 136;  // padded k-stride in halves
    __shared__ _Float16 wlds[128 * KP];  // wlds[n][k] = W[k][n]
    int t = threadIdx.x;
    int wv = t >> 6, lane = t & 63;
    int quad = lane >> 4, m16 = lane & 15;
    // stage W^T as fp16
    for (int i = t; i < 4096; i += 256) {  // 128*128/4
        int k = i >> 5;
        int n0 = (i & 31) << 2;
        float4 v = *(const float4*)(W + k * 128 + n0);
        wlds[(n0 + 0) * KP + k] = (_Float16)v.x;
        wlds[(n0 + 1) * KP + k] = (_Float16)v.y;
        wlds[(n0 + 2) * KP + k] = (_Float16)v.z;
        wlds[(n0 + 3) * KP + k] = (_Float16)v.w;
    }
    __syncthreads();

    int row = blockIdx.x * 64 + wv * 16 + m16;
    int rowC = min(row, nrows - 1);
    const float* xp = X + (size_t)rowC * 128;

    f32x4 acc[8];
#pragma unroll
    for (int nt = 0; nt < 8; ++nt) acc[nt] = (f32x4)0.f;

    for (int kt = 0; kt < 128; kt += 32) {
        float4 v0 = *(const float4*)(xp + kt + quad * 8);
        float4 v1 = *(const float4*)(xp + kt + quad * 8 + 4);
        f16x8 af;
        af[0] = (_Float16)v0.x; af[1] = (_Float16)v0.y;
        af[2] = (_Float16)v0.z; af[3] = (_Float16)v0.w;
        af[4] = (_Float16)v1.x; af[5] = (_Float16)v1.y;
        af[6] = (_Float16)v1.z; af[7] = (_Float16)v1.w;
#pragma unroll
        for (int nt = 0; nt < 8; ++nt) {
            f16x8 bf = *(const f16x8*)(&wlds[(nt * 16 + m16) * KP + kt + quad * 8]);
            acc[nt] = __builtin_amdgcn_mfma_f32_16x16x32_f16(af, bf, acc[nt], 0, 0, 0);
        }
    }

    // per-lane alpha coefficients for its column in each tile
    float aS[8], aD[8];
#pragma unroll
    for (int nt = 0; nt < 8; ++nt) {
        aS[nt] = a_src[nt * 16 + m16];
        aD[nt] = a_dst[nt * 16 + m16];
    }
    int rowBaseW = blockIdx.x * 64 + wv * 16;
#pragma unroll
    for (int r = 0; r < 4; ++r) {
        int orow = rowBaseW + quad * 4 + r;
        bool ov = orow < nrows;
        // fp16 store of C row segment
        if (ov) {
#pragma unroll
            for (int nt = 0; nt < 8; ++nt)
                outh[(size_t)orow * 128 + nt * 16 + m16] = __float2half(acc[nt][r]);
        }
        // alpha: per head h, reduce cols (2 tiles x 16 lanes)
#pragma unroll
        for (int h = 0; h < 4; ++h) {
            float ss = acc[2 * h][r] * aS[2 * h] + acc[2 * h + 1][r] * aS[2 * h + 1];
            float dd = acc[2 * h][r] * aD[2 * h] + acc[2 * h + 1][r] * aD[2 * h + 1];
#pragma unroll
            for (int o = 1; o < 16; o <<= 1) {
                ss += __shfl_xor(ss, o, 64);
                dd += __shfl_xor(dd, o, 64);
            }
            if (ov && m16 == h) {
                as_out[orow * 4 + h] = ss;
                ad_out[orow * 4 + h] = dd;
            }
        }
    }
}

// ---------------- GEMM2: h2in fp16 [n,128] @ W2 [128,64] -> h2bh fp16 + alphas --

__global__ __launch_bounds__(256) void gemm2_mfma_kernel(const __half* __restrict__ Xh,
                                                         const float* __restrict__ W,
                                                         __half* __restrict__ outh,
                                                         const float* __restrict__ a_src,
                                                         const float* __restrict__ a_dst,
                                                         float* __restrict__ as_out,
                                                         float* __restrict__ ad_out, int nrows) {
    constexpr int KP = 136;
    __shared__ _Float16 wlds[64 * KP];  // wlds[n][k] = W[k][n]
    int t = threadIdx.x;
    int wv = t >> 6, lane = t & 63;
    int quad = lane >> 4, m16 = lane & 15;
    for (int i = t; i < 2048; i += 256) {  // 128*64/4
        int k = i >> 4;
        int n0 = (i & 15) << 2;
        float4 v = *(const float4*)(W + k * 64 + n0);
        wlds[(n0 + 0) * KP + k] = (_Float16)v.x;
        wlds[(n0 + 1) * KP + k] = (_Float16)v.y;
        wlds[(n0 + 2) * KP + k] = (_Float16)v.z;
        wlds[(n0 + 3) * KP + k] = (_Float16)v.w;
    }
    __syncthreads();

    int row = blockIdx.x * 64 + wv * 16 + m16;
    int rowC = min(row, nrows - 1);
    const _Float16* xp = (const _Float16*)Xh + (size_t)rowC * 128;

    f32x4 acc[4];
#pragma unroll
    for (int nt = 0; nt < 4; ++nt) acc[nt] = (f32x4)0.f;

    for (int kt = 0; kt < 128; kt += 32) {
        f16x8 af = *(const f16x8*)(xp + kt + quad * 8);
#pragma unroll
        for (int nt = 0; nt < 4; ++nt) {
            f16x8 bf = *(const f16x8*)(&wlds[(nt * 16 + m16) * KP + kt + quad * 8]);
            acc[nt] = __builtin_amdgcn_mfma_f32_16x16x32_f16(af, bf, acc[nt], 0, 0, 0);
        }
    }

    float aS[4], aD[4];
#pragma unroll
    for (int nt = 0; nt < 4; ++nt) {
        aS[nt] = a_src[nt * 16 + m16];
        aD[nt] = a_dst[nt * 16 + m16];
    }
    int rowBaseW = blockIdx.x * 64 + wv * 16;
#pragma unroll
    for (int r = 0; r < 4; ++r) {
        int orow = rowBaseW + quad * 4 + r;
        bool ov = orow < nrows;
        if (ov) {
#pragma unroll
            for (int nt = 0; nt < 4; ++nt)
                outh[(size_t)orow * 64 + nt * 16 + m16] = __float2half(acc[nt][r]);
        }
        float ss = 0.f, dd = 0.f;
#pragma unroll
        for (int nt = 0; nt < 4; ++nt) {
            ss = fmaf(acc[nt][r], aS[nt], ss);
            dd = fmaf(acc[nt][r], aD[nt], dd);
        }
#pragma unroll
        for (int o = 1; o < 16; o <<= 1) {
            ss += __shfl_xor(ss, o, 64);
            dd += __shfl_xor(dd, o, 64);
        }
        if (ov && m16 == 0) {
            as_out[orow] = ss;
            ad_out[orow] = dd;
        }
    }
}

// ---------------- aggregation ----------------

// layer 1: one wave per dst node. Half-wave per edge row: lane = {half(1),m(5)},
// lane m covers channels [4m,4m+4) via one 8B f16x4 gather. R11: 12-edge
// batches, all 6 row-gathers + 6 asrc gathers issued before consumption
// (12 outstanding loads/lane). Guarded slots gather row 0 (L1-hot).
__global__ __launch_bounds__(256) void agg1_kernel(const __half* __restrict__ h1h,
                                                   const float* __restrict__ asrc,
                                                   const float* __restrict__ adst,
                                                   const int* __restrict__ row_ptr,
                                                   const unsigned short* __restrict__ col,
                                                   const float* __restrict__ b1,
                                                   __half* __restrict__ out, int n) {
    int wave = threadIdx.x >> 6;
    int lane = threadIdx.x & 63;
    int node = blockIdx.x * 4 + wave;
    if (node >= n) return;
    int half = lane >> 5;
    int m = lane & 31;             // f16x4 chunk index within 128-ch row
    int head = m >> 3;             // 4 heads x 8 chunks
    const char* __restrict__ h1c = (const char*)h1h;
    const char* __restrict__ asc = (const char*)asrc;
    unsigned moff = (unsigned)m << 3;    // byte offset of lane's 8B chunk (<256)
    unsigned aoff = (unsigned)head << 2; // byte offset into 16B asrc row
    float ad = adst[node * 4 + head];
    int start = row_ptr[node], end = row_ptr[node + 1];
    float a0c = 0.f, a1c = 0.f, a2c = 0.f, a3c = 0.f, s = 0.f;
    for (int base = start; base < end; base += 64) {
        int cnt = min(64, end - base);
        int idx = base + lane;
        int myS = (idx < end) ? (int)col[idx] : 0;
        for (int j = 0; j < cnt; j += 12) {
            // ---- issue phase: 6 row-gathers + 6 asrc gathers per lane ----
            int jj[6];
            int sv[6];
#pragma unroll
            for (int k = 0; k < 6; ++k) {
                jj[k] = j + 2 * k + half;          // >=64 wraps in shfl; guarded below
                sv[k] = __shfl(myS, jj[k], 64);
            }
            f16x4 v[6];
            float as[6];
#pragma unroll
            for (int k = 0; k < 6; ++k) {
                v[k]  = *(const f16x4*)(h1c + ((((unsigned)sv[k]) << 8) | moff));
                as[k] = *(const float*)(asc + ((((unsigned)sv[k]) << 4) | aoff));
            }
            // ---- consume phase ----
#pragma unroll
            for (int k = 0; k < 6; ++k) {
                float e = as[k] + ad;
                e = fmaxf(e, LRELU_SLOPE * e);
                float p = (jj[k] < cnt) ? __expf(e) : 0.f;
                a0c = fmaf(p, (float)v[k][0], a0c);
                a1c = fmaf(p, (float)v[k][1], a1c);
                a2c = fmaf(p, (float)v[k][2], a2c);
                a3c = fmaf(p, (float)v[k][3], a3c);
                s += p;
            }
        }
    }
    a0c += __shfl_xor(a0c, 32, 64);
    a1c += __shfl_xor(a1c, 32, 64);
    a2c += __shfl_xor(a2c, 32, 64);
    a3c += __shfl_xor(a3c, 32, 64);
    s   += __shfl_xor(s, 32, 64);
    if (half == 0) {
        float inv = 1.f / (s + 1e-16f);
        float4 bb = ((const float4*)b1)[m];
        f16x4 o;
        o[0] = (_Float16)fmaxf(fmaf(a0c, inv, bb.x), 0.f);  // relu between layers
        o[1] = (_Float16)fmaxf(fmaf(a1c, inv, bb.y), 0.f);
        o[2] = (_Float16)fmaxf(fmaf(a2c, inv, bb.z), 0.f);
        o[3] = (_Float16)fmaxf(fmaf(a3c, inv, bb.w), 0.f);
        ((f16x4*)out)[node * 32 + m] = o;
    }
}

// layer 2: one wave per dst node. Quarter-wave per edge row: lane = {q(2),m(4)},
// lane m covers channels [4m,4m+4) of 64. R11: 12-edge batches (3 per quarter),
// 3 row + 3 asrc gathers in flight per lane.
__global__ __launch_bounds__(256) void agg2_kernel(const __half* __restrict__ h2bh,
                                                   const float* __restrict__ asrc,
                                                   const float* __restrict__ adst,
                                                   const int* __restrict__ row_ptr,
                                                   const unsigned short* __restrict__ col,
                                                   const float* __restrict__ b2,
                                                   float* __restrict__ out, int n) {
    int wave = threadIdx.x >> 6;
    int lane = threadIdx.x & 63;
    int node = blockIdx.x * 4 + wave;
    if (node >= n) return;
    int q = lane >> 4;
    int m = lane & 15;             // f16x4 chunk index within 64-ch row
    const char* __restrict__ h2c = (const char*)h2bh;
    const char* __restrict__ asc = (const char*)asrc;
    unsigned moff = (unsigned)m << 3;   // byte offset of lane's 8B chunk (<128)
    float ad = adst[node];
    int start = row_ptr[node], end = row_ptr[node + 1];
    float a0c = 0.f, a1c = 0.f, a2c = 0.f, a3c = 0.f, s = 0.f;
    for (int base = start; base < end; base += 64) {
        int cnt = min(64, end - base);
        int idx = base + lane;
        int myS = (idx < end) ? (int)col[idx] : 0;
        for (int j = 0; j < cnt; j += 12) {
            int jj[3];
            int sv[3];
#pragma unroll
            for (int k = 0; k < 3; ++k) {
                jj[k] = j + 4 * k + q;
                sv[k] = __shfl(myS, jj[k], 64);
            }
            f16x4 v[3];
            float as[3];
#pragma unroll
            for (int k = 0; k < 3; ++k) {
                v[k]  = *(const f16x4*)(h2c + ((((unsigned)sv[k]) << 7) | moff));
                as[k] = *(const float*)(asc + (((unsigned)sv[k]) << 2));
            }
#pragma unroll
            for (int k = 0; k < 3; ++k) {
                float e = as[k] + ad;
                e = fmaxf(e, LRELU_SLOPE * e);
                float p = (jj[k] < cnt) ? __expf(e) : 0.f;
                a0c = fmaf(p, (float)v[k][0], a0c);
                a1c = fmaf(p, (float)v[k][1], a1c);
                a2c = fmaf(p, (float)v[k][2], a2c);
                a3c = fmaf(p, (float)v[k][3], a3c);
                s += p;
            }
        }
    }
#pragma unroll
    for (int o = 16; o <= 32; o <<= 1) {
        a0c += __shfl_xor(a0c, o, 64);
        a1c += __shfl_xor(a1c, o, 64);
        a2c += __shfl_xor(a2c, o, 64);
        a3c += __shfl_xor(a3c, o, 64);
        s   += __shfl_xor(s, o, 64);
    }
    if (lane < 16) {
        float inv = 1.f / (s + 1e-16f);
        float4 bb = ((const float4*)b2)[m];
        float4 o;
        o.x = fmaf(a0c, inv, bb.x);
        o.y = fmaf(a1c, inv, bb.y);
        o.z = fmaf(a2c, inv, bb.z);
        o.w = fmaf(a3c, inv, bb.w);
        ((float4*)(out + (size_t)node * 64))[m] = o;
    }
}

// ---------------- launch ----------------

extern "C" void kernel_launch(void* const* d_in, const int* in_sizes, int n_in,
                              void* d_out, int out_size, void* d_ws, size_t ws_size,
                              hipStream_t stream) {
    const float* x      = (const float*)d_in[0];
    const int*   ei     = (const int*)d_in[1];
    const float* W1     = (const float*)d_in[2];
    const float* a_src1 = (const float*)d_in[3];
    const float* a_dst1 = (const float*)d_in[4];
    const float* b1     = (const float*)d_in[5];
    const float* W2     = (const float*)d_in[6];
    const float* a_src2 = (const float*)d_in[7];
    const float* a_dst2 = (const float*)d_in[8];
    const float* b2     = (const float*)d_in[9];
    float* out = (float*)d_out;

    const int N = in_sizes[0] / 128;
    const int E = in_sizes[1] / 2;
    const int total = E + N;
    const int nBuckets = (N + 255) >> 8;   // 196

    char* ws = (char*)d_ws;
    size_t off = 0;
    auto alloc = [&](size_t bytes) {
        void* p = ws + off;
        off += (bytes + 255) & ~(size_t)255;
        return p;
    };
    // Region A: records+hist (CSR build), then h2in fp16 (agg1->gemm2).
    float* regionA = (float*)alloc((size_t)N * 128 * 4);
    __half* h1h   = (__half*)alloc((size_t)N * 128 * 2);
    __half* h2bh  = (__half*)alloc((size_t)N * 64 * 2);
    float* asrc1  = (float*)alloc((size_t)N * 4 * 4);
    float* adst1  = (float*)alloc((size_t)N * 4 * 4);
    float* asrc2  = (float*)alloc((size_t)N * 4);
    float* adst2  = (float*)alloc((size_t)N * 4);
    int*   deg    = (int*)alloc((size_t)N * 4);
    int*   row_ptr= (int*)alloc((size_t)(N + 1) * 4);
    int*   gfill  = (int*)alloc((size_t)nBuckets * 4);
    int*   bsums  = (int*)alloc((size_t)nBuckets * 4);
    unsigned short* col = (unsigned short*)alloc((size_t)total * 2);

    unsigned int* records = (unsigned int*)regionA;          // 12.8MB
    int* hist = (int*)(regionA + (size_t)NBMAX * BCAP);      // +400KB
    __half* h2in = (__half*)regionA;                         // after CSR build done
    (void)ws_size; (void)n_in; (void)out_size;

    const int* ei_src = ei;
    const int* ei_dst = ei + E;

    // CSR build (counting sort by dst bucket)
    const int chunk = (E + NBLK - 1) / NBLK;
    hist_kernel<<<NBLK, 256, 0, stream>>>(ei_dst, hist, E, chunk);
    bucket_scan_kernel<<<nBuckets, NBLK, 0, stream>>>(hist, gfill);
    scatter2_kernel<<<NBLK, 256, 0, stream>>>(ei_src, ei_dst, hist, records, E, chunk);
    deg_kernel<<<nBuckets, 256, 0, stream>>>(records, gfill, deg, N);
    scan_blocksums_kernel<<<1, 256, 0, stream>>>(gfill, bsums, row_ptr, nBuckets, N, total);
    scan_down_kernel<<<nBuckets, 256, 0, stream>>>(deg, bsums, row_ptr, N);
    csr_scatter_kernel<<<nBuckets, 256, 0, stream>>>(records, gfill, row_ptr, col, N);

    // layer 1
    gemm1_mfma_kernel<<<(N + 63) / 64, 256, 0, stream>>>(x, W1, h1h, a_src1, a_dst1,
                                                         asrc1, adst1, N);
    agg1_kernel<<<(N + 3) / 4, 256, 0, stream>>>(h1h, asrc1, adst1,
                                                 row_ptr, col, b1, h2in, N);

    // layer 2
    gemm2_mfma_kernel<<<(N + 63) / 64, 256, 0, stream>>>(h2in, W2, h2bh, a_src2, a_dst2,
                                                         asrc2, adst2, N);
    agg2_kernel<<<(N + 3) / 4, 256, 0, stream>>>(h2bh, asrc2, adst2,
                                                 row_ptr, col, b2, out, N);
}